// Round 3
// baseline (386.319 us; speedup 1.0000x reference)
//
#include <hip/hip_runtime.h>
#include <hip/hip_bf16.h>

// Fused MHA block. B=4, S=2048, D=768, H=16, DH=48, causal, LayerNorm(eps=1e-3).
// FP32 harness buffers; bf16 MFMA internally (threshold is bf16-lenient, 2% rel).
//
// Pipeline:
//   1. prep     : Wt[n][k] = bf16(W[k][n])  +  Xb = bf16(x) for q,k,v.
//   2. qkv_proj : phase-interleaved MFMA GEMM with counted vmcnt (T3+T4+T5).
//   3. attn     : MFMA flash attn, operand-swapped. NEW this round:
//                 - P stays in registers: 2-stage shfl_xor butterfly converts the
//                   QK^T C-layout (k=16t+quad*4+r) to the PV A-frag layout
//                   (k=quad*8+j). No Ps LDS buffer (was 18.4KB + conflicts).
//                 - Ks/Vs: stride-64 rows + 16B-slot XOR swizzle (slot^=row&7)
//                   on store AND read (same involution) -> 2-way reads.
//                 - LDS 50.7->28.7KB, __launch_bounds__(256,4): 4 blocks/CU.
//                 - setprio(1) around MFMA clusters.
//   4. lnorm    : vectorized LayerNorm, fp32 out.

#define DMODEL 768
#define NHEAD  16
#define DHEAD  48
#define SEQ    2048
#define NBATCH 4
#define NROWS  (NBATCH * SEQ)                 // 8192
// Q prescale: 1/sqrt(48) * log2(e)  -> softmax = single v_exp_f32 (2^x)
#define QSCALE (0.14433756729740643f * 1.4426950408889634f)

typedef __bf16 bf16x8 __attribute__((ext_vector_type(8)));
typedef float  f32x4  __attribute__((ext_vector_type(4)));

// ---------------- 1. prep: W transpose+cvt, X cvt ----------------
__global__ __launch_bounds__(256) void prep(
    const float* __restrict__ Wq,
    const float* __restrict__ Wk,
    const float* __restrict__ Wv,
    const float* __restrict__ xq,
    const float* __restrict__ xk,
    const float* __restrict__ xv,
    __hip_bfloat16* __restrict__ Wt,
    __hip_bfloat16* __restrict__ Xbq,
    __hip_bfloat16* __restrict__ Xbk,
    __hip_bfloat16* __restrict__ Xbv)
{
    int bid = blockIdx.x;
    if (bid < 1728) {
        __shared__ __hip_bfloat16 tile[32][33];
        int mat = bid / 576;
        int t   = bid - mat * 576;
        int tr  = t / 24, tc = t - (t / 24) * 24;
        const float* W = (mat == 0) ? Wq : (mat == 1) ? Wk : Wv;
        __hip_bfloat16* O = Wt + (size_t)mat * DMODEL * DMODEL;
        int tx = threadIdx.x & 31, ty = threadIdx.x >> 5;
#pragma unroll
        for (int i = 0; i < 32; i += 8)
            tile[ty + i][tx] = __float2bfloat16(W[(size_t)(tr * 32 + ty + i) * DMODEL + tc * 32 + tx]);
        __syncthreads();
#pragma unroll
        for (int i = 0; i < 32; i += 8)
            O[(size_t)(tc * 32 + ty + i) * DMODEL + tr * 32 + tx] = tile[tx][ty + i];
    } else {
        int b2  = bid - 1728;                 // 0..9215
        int mat = b2 / 3072;
        int r   = b2 - mat * 3072;
        const float* X = (mat == 0) ? xq : (mat == 1) ? xk : xv;
        __hip_bfloat16* O = (mat == 0) ? Xbq : (mat == 1) ? Xbk : Xbv;
        size_t off = (size_t)r * 2048 + threadIdx.x * 8;
        float4 f0 = *(const float4*)(X + off);
        float4 f1 = *(const float4*)(X + off + 4);
        union { __hip_bfloat16 h[8]; uint4 u; } pk;
        pk.h[0] = __float2bfloat16(f0.x); pk.h[1] = __float2bfloat16(f0.y);
        pk.h[2] = __float2bfloat16(f0.z); pk.h[3] = __float2bfloat16(f0.w);
        pk.h[4] = __float2bfloat16(f1.x); pk.h[5] = __float2bfloat16(f1.y);
        pk.h[6] = __float2bfloat16(f1.z); pk.h[7] = __float2bfloat16(f1.w);
        *(uint4*)(O + off) = pk.u;
    }
}

// ---------------- 2. QKV projection: phase-interleaved, counted vmcnt --------
__global__ __launch_bounds__(512, 4) void qkv_proj(
    const __hip_bfloat16* __restrict__ Xbq,
    const __hip_bfloat16* __restrict__ Xbk,
    const __hip_bfloat16* __restrict__ Xbv,
    const __hip_bfloat16* __restrict__ Wt,
    const float* __restrict__ bq,
    const float* __restrict__ bk,
    const float* __restrict__ bv,
    __hip_bfloat16* __restrict__ Qr,
    __hip_bfloat16* __restrict__ Kr,
    __hip_bfloat16* __restrict__ Vt)
{
    __shared__ __hip_bfloat16 Abuf[3][8192];   // 3 x 16 KiB
    __shared__ __hip_bfloat16 Bbuf[2][4096];   // 2 x  8 KiB   (total 64 KiB)

    int tid  = threadIdx.x;
    int w    = tid >> 6, lane = tid & 63;
    int l16  = lane & 15, quad = lane >> 4;
    int wm   = w >> 1, wn = w & 1;             // 4M x 2N waves

    int xcd = blockIdx.x & 7, s = blockIdx.x >> 3;
    int nt  = s % 6;
    int idx = (s / 6) * 8 + xcd;               // 0..95
    int mat = idx >> 5, mt = idx & 31;
    int m0  = mt * 256, n0 = nt * 128;

    const __hip_bfloat16* X = (mat == 0) ? Xbq : (mat == 1) ? Xbk : Xbv;
    const __hip_bfloat16* W = Wt + (size_t)mat * DMODEL * DMODEL;
    const float* bias       = (mat == 0) ? bq : (mat == 1) ? bk : bv;

    int sr = tid >> 2, sc = (tid & 3) * 8;
    const __hip_bfloat16* ga0 = X + (size_t)(m0 + sr) * DMODEL + sc;
    const __hip_bfloat16* ga1 = X + (size_t)(m0 + 128 + sr) * DMODEL + sc;
    const __hip_bfloat16* gb  = W + (size_t)(n0 + sr) * DMODEL + sc;

#define GLD(gp_, lp_) __builtin_amdgcn_global_load_lds(                        \
        (const __attribute__((address_space(1))) void*)(gp_),                  \
        (__attribute__((address_space(3))) void*)(lp_), 16, 0, 0)

    int aoff = (wm * 64 + l16) * 32 + quad * 8;
    int boff = (wn * 64 + l16) * 32 + quad * 8;

    f32x4 acc[4][4] = {};

    GLD(gb,       &Bbuf[0][tid * 8]);
    GLD(ga0,      &Abuf[0][tid * 8]);
    GLD(ga1,      &Abuf[0][4096 + tid * 8]);
    GLD(ga0 + 32, &Abuf[1][tid * 8]);
    GLD(ga1 + 32, &Abuf[1][4096 + tid * 8]);
    asm volatile("s_waitcnt vmcnt(2)" ::: "memory");
    asm volatile("s_barrier" ::: "memory");

    int abuf = 0, bbuf = 0, abS = 2;
    const __hip_bfloat16* gbS  = gb  + 32;
    const __hip_bfloat16* ga0S = ga0 + 64;
    const __hip_bfloat16* ga1S = ga1 + 64;

    for (int kt = 0; kt < 24; ++kt) {
        const __hip_bfloat16* LA = Abuf[abuf];
        const __hip_bfloat16* LB = Bbuf[bbuf];

        bf16x8 a[4], bA[2];
#pragma unroll
        for (int m_ = 0; m_ < 4; ++m_)
            a[m_] = *(const bf16x8*)&LA[aoff + m_ * 512];
        bA[0] = *(const bf16x8*)&LB[boff];
        bA[1] = *(const bf16x8*)&LB[boff + 512];

        if (kt < 23) { GLD(gbS, &Bbuf[bbuf ^ 1][tid * 8]); gbS += 32; }
        if (kt < 22) {
            GLD(ga0S, &Abuf[abS][tid * 8]);
            GLD(ga1S, &Abuf[abS][4096 + tid * 8]);
            ga0S += 32; ga1S += 32;
        }

        asm volatile("s_barrier" ::: "memory");
        __builtin_amdgcn_s_setprio(1);
#pragma unroll
        for (int m_ = 0; m_ < 4; ++m_) {
            acc[m_][0] = __builtin_amdgcn_mfma_f32_16x16x32_bf16(a[m_], bA[0], acc[m_][0], 0, 0, 0);
            acc[m_][1] = __builtin_amdgcn_mfma_f32_16x16x32_bf16(a[m_], bA[1], acc[m_][1], 0, 0, 0);
        }
        __builtin_amdgcn_s_setprio(0);
        asm volatile("s_barrier" ::: "memory");

        bf16x8 bB[2];
        bB[0] = *(const bf16x8*)&LB[boff + 1024];
        bB[1] = *(const bf16x8*)&LB[boff + 1536];

        if (kt < 22) asm volatile("s_waitcnt vmcnt(2)" ::: "memory");
        else         asm volatile("s_waitcnt vmcnt(0)" ::: "memory");
        asm volatile("s_barrier" ::: "memory");
        __builtin_amdgcn_s_setprio(1);
#pragma unroll
        for (int m_ = 0; m_ < 4; ++m_) {
            acc[m_][2] = __builtin_amdgcn_mfma_f32_16x16x32_bf16(a[m_], bB[0], acc[m_][2], 0, 0, 0);
            acc[m_][3] = __builtin_amdgcn_mfma_f32_16x16x32_bf16(a[m_], bB[1], acc[m_][3], 0, 0, 0);
        }
        __builtin_amdgcn_s_setprio(0);
        asm volatile("s_barrier" ::: "memory");

        abuf = (abuf == 2) ? 0 : abuf + 1;
        abS  = (abS  == 2) ? 0 : abS  + 1;
        bbuf ^= 1;
    }
#undef GLD

    // epilogue
#pragma unroll
    for (int j = 0; j < 4; ++j) {
        int col = n0 + wn * 64 + j * 16 + l16;
        float bc = bias[col];
        if (mat == 0) {
#pragma unroll
            for (int i = 0; i < 4; ++i) {
                int row0 = m0 + wm * 64 + i * 16 + quad * 4;
#pragma unroll
                for (int r = 0; r < 4; ++r)
                    Qr[(size_t)(row0 + r) * DMODEL + col] =
                        __float2bfloat16((acc[i][j][r] + bc) * QSCALE);
            }
        } else if (mat == 1) {
#pragma unroll
            for (int i = 0; i < 4; ++i) {
                int row0 = m0 + wm * 64 + i * 16 + quad * 4;
#pragma unroll
                for (int r = 0; r < 4; ++r)
                    Kr[(size_t)(row0 + r) * DMODEL + col] =
                        __float2bfloat16(acc[i][j][r] + bc);
            }
        } else {
            int h = col / 48, dh = col - h * 48;
#pragma unroll
            for (int i = 0; i < 4; ++i) {
                int row0 = m0 + wm * 64 + i * 16 + quad * 4;
                int bb = row0 >> 11, s0 = row0 & 2047;
                ushort4 pk;
                union { __hip_bfloat16 b; unsigned short u; } cv;
                cv.b = __float2bfloat16(acc[i][j][0] + bc); pk.x = cv.u;
                cv.b = __float2bfloat16(acc[i][j][1] + bc); pk.y = cv.u;
                cv.b = __float2bfloat16(acc[i][j][2] + bc); pk.z = cv.u;
                cv.b = __float2bfloat16(acc[i][j][3] + bc); pk.w = cv.u;
                *(ushort4*)(Vt + ((size_t)(bb * NHEAD + h) * DHEAD + dh) * SEQ + s0) = pk;
            }
        }
    }
}

// ---------------- 3. MFMA causal flash attention, register-resident P ------------
// K tile: Ks[buf][64][64] (cols 48..63 zero), V^T tile: Vs[buf][48][64].
// 16B-slot XOR swizzle (slot ^= row&7) on BOTH store and read -> conflict-free-ish.
// P never touches LDS: 2-stage shfl_xor butterfly remaps QK^T output regs
// (k = 16t + quad*4 + r, packed as bf16 pairs kp = 8t + 2*quad + p) into the
// PV A-frag layout (k = quad*8 + j).
__global__ __launch_bounds__(256, 4) void attn(
    const __hip_bfloat16* __restrict__ Qr,
    const __hip_bfloat16* __restrict__ Kr,
    const __hip_bfloat16* __restrict__ Vt,
    __hip_bfloat16* __restrict__ Ao)
{
    __shared__ __hip_bfloat16 Ks[2][64][64];   // 16 KiB
    __shared__ __hip_bfloat16 Vs[2][48][64];   // 12 KiB  (total 28 KiB)

    int tid  = threadIdx.x;
    int w    = tid >> 6, lane = tid & 63;
    int l16  = lane & 15, quad = lane >> 4;
    bool b1  = (quad & 2) != 0, b0 = (quad & 1) != 0;
    int bh   = blockIdx.x & 63;
    int qt   = 15 - (blockIdx.x >> 6);         // heavy q-tiles dispatch first
    int q0   = qt * 128;
    int b    = bh >> 4, h = bh & 15;
    size_t rowbase = (size_t)b * SEQ;

    const __hip_bfloat16* Qp = Qr + rowbase * DMODEL + h * DHEAD;
    const __hip_bfloat16* Kp = Kr + rowbase * DMODEL + h * DHEAD;
    const __hip_bfloat16* Vp = Vt + (size_t)bh * DHEAD * SEQ;

    // zero the swizzled pad slots (logical cols 48..63) of both K buffers:
    // 256 chunks = 2 buf x 64 row x 2 slot, one per thread
    {
        int zbuf = tid >> 7, zr = (tid >> 1) & 63, zsl = 6 + (tid & 1);
        *(uint4*)&Ks[zbuf][zr][(zsl ^ (zr & 7)) * 8] = (uint4){0u, 0u, 0u, 0u};
    }

    bf16x8 bQ0[2], bQ1[2];
#pragma unroll
    for (int i = 0; i < 2; ++i) {
        int qrow = q0 + w * 32 + i * 16 + l16;
        bQ0[i] = *(const bf16x8*)(Qp + (size_t)qrow * DMODEL + quad * 8);
        bQ1[i] = (bf16x8){};
        if (quad < 2)
            bQ1[i] = *(const bf16x8*)(Qp + (size_t)qrow * DMODEL + 32 + quad * 8);
    }

    // staging chunk maps: K = 384 chunks (64 rows x 6 slots of 16B),
    //                     V = 384 chunks (48 rows x 8 slots of 16B).
    // thread t handles chunk t; threads <128 also handle chunk 256+t.
    int kr1 = tid / 6,          ksl1 = tid - kr1 * 6;
    int kr2 = (tid + 256) / 6,  ksl2 = (tid + 256) - kr2 * 6;
    int vd1 = tid >> 3,         vsl1 = tid & 7;
    int vd2 = (tid + 256) >> 3, vsl2 = tid & 7;
    int kso1 = (ksl1 ^ (kr1 & 7)) * 8;
    int kso2 = (ksl2 ^ (kr2 & 7)) * 8;
    int vso1 = (vsl1 ^ (vd1 & 7)) * 8;
    int vso2 = (vsl2 ^ (vd2 & 7)) * 8;

    uint4 kv1, kv2, vv1, vv2;

#define ATTN_LOAD(kt_) {                                                        \
        int k0_ = (kt_) * 64;                                                   \
        kv1 = *(const uint4*)(Kp + (size_t)(k0_ + kr1) * DMODEL + ksl1 * 8);    \
        vv1 = *(const uint4*)(Vp + (size_t)vd1 * SEQ + k0_ + vsl1 * 8);         \
        if (tid < 128) {                                                        \
            kv2 = *(const uint4*)(Kp + (size_t)(k0_ + kr2) * DMODEL + ksl2 * 8);\
            vv2 = *(const uint4*)(Vp + (size_t)vd2 * SEQ + k0_ + vsl2 * 8);     \
        } }

#define ATTN_STORE(buf_) {                                                      \
        *(uint4*)&Ks[buf_][kr1][kso1] = kv1;                                    \
        *(uint4*)&Vs[buf_][vd1][vso1] = vv1;                                    \
        if (tid < 128) {                                                        \
            *(uint4*)&Ks[buf_][kr2][kso2] = kv2;                                \
            *(uint4*)&Vs[buf_][vd2][vso2] = vv2;                                \
        } }

    f32x4 O[2][3] = {};
    float lsum[2] = {0.f, 0.f};
    const f32x4 zf = {};

    // swizzled read slots: row&7 == l16&7 for every frag row (16t+l16)
    int sA0 = (quad ^ (l16 & 7)) * 8;          // k-cols  0..31
    int sA1 = ((quad + 4) ^ (l16 & 7)) * 8;    // k-cols 32..63

    int ktmax = 2 * qt + 1;
    ATTN_LOAD(0);
    ATTN_STORE(0);
    if (ktmax >= 1) ATTN_LOAD(1);
    __syncthreads();

    for (int kt = 0; kt <= ktmax; ++kt) {
        int buf = kt & 1;
        int k0  = kt * 64;
        if (kt + 1 <= ktmax) ATTN_STORE(buf ^ 1);
        if (kt + 2 <= ktmax) ATTN_LOAD(kt + 2);

        bf16x8 aK0[4], aK1[4];
#pragma unroll
        for (int t = 0; t < 4; ++t) {
            aK0[t] = *(const bf16x8*)&Ks[buf][16 * t + l16][sA0];
            aK1[t] = *(const bf16x8*)&Ks[buf][16 * t + l16][sA1];
        }
        bf16x8 bV0[3], bV1[3];
#pragma unroll
        for (int dt = 0; dt < 3; ++dt) {
            bV0[dt] = *(const bf16x8*)&Vs[buf][dt * 16 + l16][sA0];
            bV1[dt] = *(const bf16x8*)&Vs[buf][dt * 16 + l16][sA1];
        }

#pragma unroll
        for (int i = 0; i < 2; ++i) {
            int qbase = q0 + w * 32 + i * 16;
            if (k0 > qbase + 15) continue;     // wave-uniform skip

            f32x4 s[4];
            __builtin_amdgcn_s_setprio(1);
#pragma unroll
            for (int t = 0; t < 4; ++t) {
                f32x4 z = __builtin_amdgcn_mfma_f32_16x16x32_bf16(aK0[t], bQ0[i], zf, 0, 0, 0);
                s[t]    = __builtin_amdgcn_mfma_f32_16x16x32_bf16(aK1[t], bQ1[i], z,  0, 0, 0);
            }
            __builtin_amdgcn_s_setprio(0);

            if (k0 + 63 > qbase) {
                int qg = qbase + l16;
#pragma unroll
                for (int t = 0; t < 4; ++t) {
                    int kg = k0 + 16 * t + quad * 4;
#pragma unroll
                    for (int r = 0; r < 4; ++r)
                        if (kg + r > qg) s[t][r] = -1e30f;
                }
            }

            // exp2 + pack: u[t][p] = bf16pair(P[k=16t+4q+2p], P[k=..+1]), kp=8t+2q+p
            float ls = 0.f;
            unsigned int u_[4][2];
#pragma unroll
            for (int t = 0; t < 4; ++t) {
                float p0 = exp2f(s[t][0]), p1 = exp2f(s[t][1]);
                float p2 = exp2f(s[t][2]), p3 = exp2f(s[t][3]);
                ls += (p0 + p1) + (p2 + p3);
                union { __hip_bfloat16 hh[2]; unsigned int ww; } pa, pb;
                pa.hh[0] = __float2bfloat16(p0); pa.hh[1] = __float2bfloat16(p1);
                pb.hh[0] = __float2bfloat16(p2); pb.hh[1] = __float2bfloat16(p3);
                u_[t][0] = pa.ww; u_[t][1] = pb.ww;
            }
            lsum[i] += ls;

            // stage 1 (xor 32): low-quads send u[1],u[3]; high-quads send u[0],u[2]
            unsigned int rA0 = __shfl_xor(b1 ? u_[0][0] : u_[1][0], 32, 64);
            unsigned int rA1 = __shfl_xor(b1 ? u_[0][1] : u_[1][1], 32, 64);
            unsigned int rB0 = __shfl_xor(b1 ? u_[2][0] : u_[3][0], 32, 64);
            unsigned int rB1 = __shfl_xor(b1 ? u_[2][1] : u_[3][1], 32, 64);
            unsigned int X00 = b1 ? rA0 : u_[0][0], X01 = b1 ? rA1 : u_[0][1];
            unsigned int X10 = b1 ? u_[1][0] : rA0, X11 = b1 ? u_[1][1] : rA1;
            unsigned int X20 = b1 ? rB0 : u_[2][0], X21 = b1 ? rB1 : u_[2][1];
            unsigned int X30 = b1 ? u_[3][0] : rB0, X31 = b1 ? u_[3][1] : rB1;
            // stage 2 (xor 16): even quads send X1,X3; odd quads send X0,X2
            unsigned int rC0 = __shfl_xor(b0 ? X00 : X10, 16, 64);
            unsigned int rC1 = __shfl_xor(b0 ? X01 : X11, 16, 64);
            unsigned int rD0 = __shfl_xor(b0 ? X20 : X30, 16, 64);
            unsigned int rD1 = __shfl_xor(b0 ? X21 : X31, 16, 64);

            union { unsigned int ww[4]; bf16x8 v; } P0u, P1u;
            P0u.ww[0] = b0 ? rC0 : X00;  P0u.ww[1] = b0 ? rC1 : X01;
            P0u.ww[2] = b0 ? X10 : rC0;  P0u.ww[3] = b0 ? X11 : rC1;
            P1u.ww[0] = b0 ? rD0 : X20;  P1u.ww[1] = b0 ? rD1 : X21;
            P1u.ww[2] = b0 ? X30 : rD0;  P1u.ww[3] = b0 ? X31 : rD1;

            __builtin_amdgcn_s_setprio(1);
#pragma unroll
            for (int dt = 0; dt < 3; ++dt) {
                O[i][dt] = __builtin_amdgcn_mfma_f32_16x16x32_bf16(P0u.v, bV0[dt], O[i][dt], 0, 0, 0);
                O[i][dt] = __builtin_amdgcn_mfma_f32_16x16x32_bf16(P1u.v, bV1[dt], O[i][dt], 0, 0, 0);
            }
            __builtin_amdgcn_s_setprio(0);
        }

        asm volatile("s_waitcnt lgkmcnt(0)" ::: "memory");
        __builtin_amdgcn_s_barrier();
        asm volatile("" ::: "memory");
    }

#pragma unroll
    for (int i = 0; i < 2; ++i) {
        lsum[i] += __shfl_xor(lsum[i], 16, 64);
        lsum[i] += __shfl_xor(lsum[i], 32, 64);
    }

#pragma unroll
    for (int i = 0; i < 2; ++i) {
#pragma unroll
        for (int r = 0; r < 4; ++r) {
            float linv = 1.f / __shfl(lsum[i], quad * 4 + r, 64);
            size_t g = (rowbase + q0 + w * 32 + i * 16 + quad * 4 + r) * DMODEL + h * DHEAD + l16;
            Ao[g + 0]  = __float2bfloat16(O[i][0][r] * linv);
            Ao[g + 16] = __float2bfloat16(O[i][1][r] * linv);
            Ao[g + 32] = __float2bfloat16(O[i][2][r] * linv);
        }
    }
#undef ATTN_LOAD
#undef ATTN_STORE
}

// ---------------- 4. LayerNorm (eps = 1e-3), vectorized, fp32 out ----------------
__global__ __launch_bounds__(192) void lnorm(
    const __hip_bfloat16* __restrict__ Ao,
    const float* __restrict__ gamma,
    const float* __restrict__ beta,
    float* __restrict__ out)
{
    __shared__ float rs_[3], rq_[3];
    int row = blockIdx.x;
    int t   = threadIdx.x;
    size_t base = (size_t)row * DMODEL + t * 4;

    ushort4 u = *(const ushort4*)(Ao + base);
    float x0, x1, x2, x3;
    { unsigned int v = (unsigned int)u.x << 16; __builtin_memcpy(&x0, &v, 4); }
    { unsigned int v = (unsigned int)u.y << 16; __builtin_memcpy(&x1, &v, 4); }
    { unsigned int v = (unsigned int)u.z << 16; __builtin_memcpy(&x2, &v, 4); }
    { unsigned int v = (unsigned int)u.w << 16; __builtin_memcpy(&x3, &v, 4); }

    float s = x0 + x1 + x2 + x3;
    float q = x0 * x0 + x1 * x1 + x2 * x2 + x3 * x3;
#pragma unroll
    for (int m = 32; m >= 1; m >>= 1) {
        s += __shfl_xor(s, m, 64);
        q += __shfl_xor(q, m, 64);
    }
    int wv = t >> 6;
    if ((t & 63) == 0) { rs_[wv] = s; rq_[wv] = q; }
    __syncthreads();
    float ts = rs_[0] + rs_[1] + rs_[2];
    float tq = rq_[0] + rq_[1] + rq_[2];
    float mu  = ts * (1.f / 768.f);
    float var = tq * (1.f / 768.f) - mu * mu;
    float rstd = rsqrtf(var + 1e-3f);

    float4 g  = *(const float4*)(gamma + t * 4);
    float4 be = *(const float4*)(beta + t * 4);
    float4 o;
    o.x = (x0 - mu) * rstd * g.x + be.x;
    o.y = (x1 - mu) * rstd * g.y + be.y;
    o.z = (x2 - mu) * rstd * g.z + be.z;
    o.w = (x3 - mu) * rstd * g.w + be.w;
    *(float4*)(out + base) = o;
}

extern "C" void kernel_launch(void* const* d_in, const int* in_sizes, int n_in,
                              void* d_out, int out_size, void* d_ws, size_t ws_size,
                              hipStream_t stream) {
    const float* q     = (const float*)d_in[0];
    const float* k     = (const float*)d_in[1];
    const float* v     = (const float*)d_in[2];
    const float* Wq    = (const float*)d_in[3];
    const float* bq    = (const float*)d_in[4];
    const float* Wk    = (const float*)d_in[5];
    const float* bk    = (const float*)d_in[6];
    const float* Wv    = (const float*)d_in[7];
    const float* bv    = (const float*)d_in[8];
    const float* gamma = (const float*)d_in[9];
    const float* beta  = (const float*)d_in[10];

    char* basep = (char*)d_ws;
    __hip_bfloat16* Wt = (__hip_bfloat16*)basep;
    __hip_bfloat16* Qr = (__hip_bfloat16*)(basep + 3538944);
    __hip_bfloat16* Kr = Qr + (size_t)NROWS * DMODEL;
    __hip_bfloat16* Vt = Kr + (size_t)NROWS * DMODEL;
    __hip_bfloat16* Ao = Vt + (size_t)NROWS * DMODEL;
    float* out = (float*)d_out;

    __hip_bfloat16* Xbq = (__hip_bfloat16*)d_out;
    __hip_bfloat16* Xbk = Xbq + (size_t)NROWS * DMODEL;
    __hip_bfloat16* Xbv = Ao;

    hipLaunchKernelGGL(prep, dim3(10944), dim3(256), 0, stream,
                       Wq, Wk, Wv, q, k, v, Wt, Xbq, Xbk, Xbv);
    hipLaunchKernelGGL(qkv_proj, dim3(576), dim3(512), 0, stream,
                       Xbq, Xbk, Xbv, Wt, bq, bk, bv, Qr, Kr, Vt);
    hipLaunchKernelGGL(attn, dim3(1024), dim3(256), 0, stream, Qr, Kr, Vt, Ao);
    hipLaunchKernelGGL(lnorm, dim3(8192), dim3(192), 0, stream, Ao, gamma, beta, out);
}